// Round 11
// baseline (60.862 us; speedup 1.0000x reference)
//
#include <hip/hip_runtime.h>

// PewLSTM HS=1, 2-lane systolic x 2 SEQUENCES PER LANE (R11).
// Even lane = layer1, odd lane = layer2 (1-step lag), h via DPP quad_perm.
// Each lane-pair processes sequences p and p+16384 INTERLEAVED: the second
// sequence's instructions fill the first's dependency-chain stalls (the
// fitted model wall = 3.6cy*N + 280cy chain says TLP/ILP across seqs is the
// only remaining lever; hw transcendentals kept -- soft ones cost more in
// issue than they save in chain).

constexpr int TT  = 168;
constexpr int CHV = 10;           // float4 per chunk
constexpr int NCH = 21;           // chunks
constexpr int HALF = 16384;       // seqs per half

#define LOG2E  1.44269504088896341f
#define NEG2L  (-2.88539008177792681f)
#define PCL    38.0f              // pre-act clamp (den products < 2^124)

#define EL(B,i) ((i)%4==0?(B)[(i)/4].x:((i)%4==1?(B)[(i)/4].y:((i)%4==2?(B)[(i)/4].z:(B)[(i)/4].w)))

__device__ __forceinline__ float lane_swap(float x) {   // quad_perm(1,0,3,2)
    return __int_as_float(
        __builtin_amdgcn_mov_dpp(__float_as_int(x), 0xB1, 0xF, 0xF, true));
}

__device__ __forceinline__ void build4(
    float w0, float w1, float w2, float w3, float xi,
    const float (&wwh)[16], const float (&wih)[4], const float (&bbv)[4],
    float& p0, float& p1, float& p2, float& p3)
{
    p0 = bbv[0]; p1 = bbv[1]; p2 = bbv[2]; p3 = bbv[3];
    p0 = fmaf(w0, wwh[0],  p0); p1 = fmaf(w0, wwh[1],  p1);
    p2 = fmaf(w0, wwh[2],  p2); p3 = fmaf(w0, wwh[3],  p3);
    p0 = fmaf(w1, wwh[4],  p0); p1 = fmaf(w1, wwh[5],  p1);
    p2 = fmaf(w1, wwh[6],  p2); p3 = fmaf(w1, wwh[7],  p3);
    p0 = fmaf(w2, wwh[8],  p0); p1 = fmaf(w2, wwh[9],  p1);
    p2 = fmaf(w2, wwh[10], p2); p3 = fmaf(w2, wwh[11], p3);
    p0 = fmaf(w3, wwh[12], p0); p1 = fmaf(w3, wwh[13], p1);
    p2 = fmaf(w3, wwh[14], p2); p3 = fmaf(w3, wwh[15], p3);
    p0 = fmaf(xi, wih[0], p0);  p1 = fmaf(xi, wih[1], p1);
    p2 = fmaf(xi, wih[2], p2);  p3 = fmaf(xi, wih[3], p3);
    p0 = fminf(p0, PCL); p1 = fminf(p1, PCL);
    p2 = fminf(p2, PCL); p3 = fminf(p3, PCL);
}

__device__ __forceinline__ void cell(
    float& h, float& cc, float h1x, float l2f,
    const float (&wih)[4], const float (&whh)[4],
    float p0, float p1, float p2, float p3)
{
    const float inv = h1x * l2f;               // L2: h1(t-1); L1: 0
    const float a0 = fmaf(h, whh[0], fmaf(inv, wih[0], p0));
    const float a1 = fmaf(h, whh[1], fmaf(inv, wih[1], p1));
    const float a2 = fmaf(h, whh[2], fmaf(inv, wih[2], p2));
    const float a3 = fmaf(h, whh[3], fmaf(inv, wih[3], p3));
    const float eI = __builtin_amdgcn_exp2f(a0);   // e^{-a_i}
    const float eF = __builtin_amdgcn_exp2f(a1);   // e^{-a_f}
    const float eG = __builtin_amdgcn_exp2f(a2);   // e^{-2a_g}
    const float eO = __builtin_amdgcn_exp2f(a3);   // e^{-a_o}
    const float dI = 1.f + eI, dF = 1.f + eF;
    const float dG = 1.f + eG, dO = 1.f + eO;
    const float nG = 1.f - eG;
    // c' = (c*dI*dG + nG*dF) / (dF*dI*dG)
    const float p   = dI * dG;
    const float num = fmaf(cc, p, nG * dF);
    cc = num * __builtin_amdgcn_rcpf(dF * p);
    // h = (1-eC)/(dO*(1+eC)), eC = 2^{min(c'*-2log2e, 40)}
    const float Cm = fminf(cc * NEG2L, 40.0f);
    const float eC = __builtin_amdgcn_exp2f(Cm);
    h = (1.f - eC) * __builtin_amdgcn_rcpf(dO * (1.f + eC));
}

__global__ __launch_bounds__(64, 1) void pewlstm_kernel(
    const float* __restrict__ in,
    const float* __restrict__ W1ih, const float* __restrict__ W1hh,
    const float* __restrict__ W1wh, const float* __restrict__ b1,
    const float* __restrict__ W2ih, const float* __restrict__ W2hh,
    const float* __restrict__ W2wh, const float* __restrict__ b2,
    const float* __restrict__ fcw, const float* __restrict__ fcb,
    float* __restrict__ out)
{
    const int tid = blockIdx.x * 64 + threadIdx.x;
    const int p   = tid >> 1;            // pair index = seq A id
    const int l2  = tid & 1;             // 1 = layer-2 lane
    const float l2f = l2 ? 1.0f : 0.0f;

    const float* Wih = l2 ? W2ih : W1ih;
    const float* Whh = l2 ? W2hh : W1hh;
    const float* Wwh = l2 ? W2wh : W1wh;
    const float* Bv  = l2 ? b2   : b1;

    // gate order [i,f,g,o]; pre-scale by -log2e (g gate: -2log2e)
    float wih[4], whh[4], bbv[4], wwh[16];
#pragma unroll
    for (int g = 0; g < 4; ++g) {
        const float s = (g == 2) ? NEG2L : -LOG2E;
        wih[g] = Wih[g] * s; whh[g] = Whh[g] * s; bbv[g] = Bv[g] * s;
    }
#pragma unroll
    for (int k = 0; k < 16; ++k) {
        const float s = ((k & 3) == 2) ? NEG2L : -LOG2E;
        wwh[k] = Wwh[k] * s;
    }
    const float fw = fcw[0], fbv = fcb[0];

    const float4* __restrict__ rowA =
        reinterpret_cast<const float4*>(in + (size_t)p * (TT * 5));
    const float4* __restrict__ rowB =
        reinterpret_cast<const float4*>(in + (size_t)(p + HALF) * (TT * 5));
    float4* orowA = reinterpret_cast<float4*>(out + (size_t)p * TT);
    float4* orowB = reinterpret_cast<float4*>(out + (size_t)(p + HALF) * TT);

    float4 bA0[CHV], bA1[CHV], bB0[CHV], bB1[CHV];
    float hA = 0.f, ccA = 0.f, h1xA = 0.f;
    float hB = 0.f, ccB = 0.f, h1xB = 0.f;
    float xcA0 = 0.f, xcA1 = 0.f, xcA2 = 0.f, xcA3 = 0.f;
    float xcB0 = 0.f, xcB1 = 0.f, xcB2 = 0.f, xcB3 = 0.f;
    float obA[8], obB[8];

    auto load = [&](float4 (&BA)[CHV], float4 (&BB)[CHV], int c2) {
#pragma unroll
        for (int i = 0; i < CHV; ++i) BA[i] = rowA[c2 * CHV + i];
#pragma unroll
        for (int i = 0; i < CHV; ++i) BB[i] = rowB[c2 * CHV + i];
    };

    auto do_chunk = [&](float4 (&BA)[CHV], float4 (&BB)[CHV], int c, bool is0) {
#pragma unroll
        for (int s = 0; s < 8; ++s) {
            // per-lane step inputs: L1 -> step t, L2 -> step t-1
            const float wA0 = l2 ? (s == 0 ? xcA0 : EL(BA,(s-1)*5+0)) : EL(BA,s*5+0);
            const float wA1 = l2 ? (s == 0 ? xcA1 : EL(BA,(s-1)*5+1)) : EL(BA,s*5+1);
            const float wA2 = l2 ? (s == 0 ? xcA2 : EL(BA,(s-1)*5+2)) : EL(BA,s*5+2);
            const float wA3 = l2 ? (s == 0 ? xcA3 : EL(BA,(s-1)*5+3)) : EL(BA,s*5+3);
            const float xiA = l2 ? 0.0f : EL(BA,s*5+4);
            const float wB0 = l2 ? (s == 0 ? xcB0 : EL(BB,(s-1)*5+0)) : EL(BB,s*5+0);
            const float wB1 = l2 ? (s == 0 ? xcB1 : EL(BB,(s-1)*5+1)) : EL(BB,s*5+1);
            const float wB2 = l2 ? (s == 0 ? xcB2 : EL(BB,(s-1)*5+2)) : EL(BB,s*5+2);
            const float wB3 = l2 ? (s == 0 ? xcB3 : EL(BB,(s-1)*5+3)) : EL(BB,s*5+3);
            const float xiB = l2 ? 0.0f : EL(BB,s*5+4);

            float pA0, pA1, pA2, pA3, pB0, pB1, pB2, pB3;
            build4(wA0, wA1, wA2, wA3, xiA, wwh, wih, bbv, pA0, pA1, pA2, pA3);
            build4(wB0, wB1, wB2, wB3, xiB, wwh, wih, bbv, pB0, pB1, pB2, pB3);

            cell(hA, ccA, h1xA, l2f, wih, whh, pA0, pA1, pA2, pA3);
            cell(hB, ccB, h1xB, l2f, wih, whh, pB0, pB1, pB2, pB3);

            if (s == 0 && is0 && l2) {     // phantom-step reset (both seqs)
                hA = 0.f; ccA = 0.f; hB = 0.f; ccB = 0.f;
            }

            obA[(s + 7) & 7] = fmaf(hA, fw, fbv);   // true h2 on l2 lane
            obB[(s + 7) & 7] = fmaf(hB, fw, fbv);

            if (s == 0 && c >= 1 && l2) {  // flush previous chunk's outputs
                orowA[(c-1)*2+0] = make_float4(obA[0], obA[1], obA[2], obA[3]);
                orowA[(c-1)*2+1] = make_float4(obA[4], obA[5], obA[6], obA[7]);
                orowB[(c-1)*2+0] = make_float4(obB[0], obB[1], obB[2], obB[3]);
                orowB[(c-1)*2+1] = make_float4(obB[4], obB[5], obB[6], obB[7]);
            }

            h1xA = lane_swap(hA);          // partner's h (L2 gets h1(t))
            h1xB = lane_swap(hB);
        }
        xcA0 = EL(BA,35); xcA1 = EL(BA,36); xcA2 = EL(BA,37); xcA3 = EL(BA,38);
        xcB0 = EL(BB,35); xcB1 = EL(BB,36); xcB2 = EL(BB,37); xcB3 = EL(BB,38);
    };

    // prologue: chunks 0 and 1 in flight
    load(bA0, bB0, 0);
    load(bA1, bB1, 1);

    for (int cp = 0; cp < 10; ++cp) {
        const int c0 = 2 * cp;
        do_chunk(bA0, bB0, c0, cp == 0);
        load(bA0, bB0, c0 + 2);            // c0+2 <= 20 for cp <= 9
        do_chunk(bA1, bB1, c0 + 1, false);
        if (c0 + 3 < NCH) load(bA1, bB1, c0 + 3);
    }
    do_chunk(bA0, bB0, 20, false);

    // epilogue iteration t=168: L2 lanes compute h2(167) for both seqs
    {
        float pA0, pA1, pA2, pA3, pB0, pB1, pB2, pB3;
        build4(xcA0, xcA1, xcA2, xcA3, 0.f, wwh, wih, bbv, pA0, pA1, pA2, pA3);
        build4(xcB0, xcB1, xcB2, xcB3, 0.f, wwh, wih, bbv, pB0, pB1, pB2, pB3);
        cell(hA, ccA, h1xA, 1.0f, wih, whh, pA0, pA1, pA2, pA3);
        cell(hB, ccB, h1xB, 1.0f, wih, whh, pB0, pB1, pB2, pB3);
        obA[7] = fmaf(hA, fw, fbv);
        obB[7] = fmaf(hB, fw, fbv);
        if (l2) {
            orowA[(NCH-1)*2+0] = make_float4(obA[0], obA[1], obA[2], obA[3]);
            orowA[(NCH-1)*2+1] = make_float4(obA[4], obA[5], obA[6], obA[7]);
            orowB[(NCH-1)*2+0] = make_float4(obB[0], obB[1], obB[2], obB[3]);
            orowB[(NCH-1)*2+1] = make_float4(obB[4], obB[5], obB[6], obB[7]);
        }
    }
}

extern "C" void kernel_launch(void* const* d_in, const int* in_sizes, int n_in,
                              void* d_out, int out_size, void* d_ws, size_t ws_size,
                              hipStream_t stream) {
    const float* in   = (const float*)d_in[0];
    const float* W1ih = (const float*)d_in[1];
    const float* W1hh = (const float*)d_in[2];
    const float* W1wh = (const float*)d_in[3];
    const float* b1   = (const float*)d_in[4];
    const float* W2ih = (const float*)d_in[5];
    const float* W2hh = (const float*)d_in[6];
    const float* W2wh = (const float*)d_in[7];
    const float* b2   = (const float*)d_in[8];
    const float* fcw  = (const float*)d_in[9];
    const float* fcb  = (const float*)d_in[10];
    float* out = (float*)d_out;

    // 2 lanes/seq-pair-slot, 2 seqs/lane: 16384 pairs * 2 lanes = 32768
    // threads = 512 waves; each wave carries 64 sequences' chains.
    pewlstm_kernel<<<512, 64, 0, stream>>>(
        in, W1ih, W1hh, W1wh, b1, W2ih, W2hh, W2wh, b2, fcw, fcb, out);
}